// Round 5
// baseline (2016.349 us; speedup 1.0000x reference)
//
#include <hip/hip_runtime.h>

#define NTOT 262144
#define CIN  256
#define MID  64
#define KOFF 9
#define EPS  1e-5f

// ---------------------------------------------------------------------------
// mask dtype sniffer: classify nbr_mask storage as int32 / uint8 / float32.
// mode 0: int32 bool (all sampled words in {0,1})
// mode 1: packed uint8 bool (some word >1, all bytes in {0,1})
// mode 2: float32 (word == 0x3F800000 seen)
// ---------------------------------------------------------------------------
__global__ __launch_bounds__(256) void detect_mask(const unsigned int* __restrict__ m,
                                                   int* __restrict__ flag)
{
    __shared__ int sF, sB;
    if (threadIdx.x == 0) { sF = 0; sB = 0; }
    __syncthreads();
    int anyF = 0, anyB = 0;
    for (int i = threadIdx.x; i < 4096; i += 256) {
        unsigned w = m[i];
        if (w == 0x3F800000u) anyF = 1;
        if (w > 1u && (w & 0xFEFEFEFEu) == 0u) anyB = 1;
    }
    if (anyF) atomicOr(&sF, 1);
    if (anyB) atomicOr(&sB, 1);
    __syncthreads();
    if (threadIdx.x == 0) *flag = sF ? 2 : (sB ? 1 : 0);
}

// ---------------------------------------------------------------------------
// micro GEMM: acc[4][4] += A[64][K] * B[K][64] tile product, K=64.
// ---------------------------------------------------------------------------
__device__ __forceinline__ void micro_gemm(const float (*A)[68], const float (*B)[64],
                                           int ty, int tx, float acc[4][4]) {
#pragma unroll
    for (int k4 = 0; k4 < 16; ++k4) {
        float bb[4][4];
#pragma unroll
        for (int kk = 0; kk < 4; ++kk)
            *reinterpret_cast<float4*>(&bb[kk][0]) =
                *reinterpret_cast<const float4*>(&B[k4 * 4 + kk][tx * 4]);
#pragma unroll
        for (int i = 0; i < 4; ++i) {
            float4 a = *reinterpret_cast<const float4*>(&A[ty * 4 + i][k4 * 4]);
#pragma unroll
            for (int j = 0; j < 4; ++j)
                acc[i][j] += a.x * bb[0][j] + a.y * bb[1][j] + a.z * bb[2][j] + a.w * bb[3][j];
        }
    }
}

// ---------------------------------------------------------------------------
// K1: h2 = relu(BN2( relu(BN1(x)) @ w1 + b1 ))          [N,256] -> [N,64]
// ---------------------------------------------------------------------------
__global__ __launch_bounds__(256) void k1_bn_gemm_bn(
    const float* __restrict__ x,
    const float* __restrict__ g1, const float* __restrict__ be1,
    const float* __restrict__ mu1, const float* __restrict__ va1,
    const float* __restrict__ w1, const float* __restrict__ b1,
    const float* __restrict__ g2, const float* __restrict__ be2,
    const float* __restrict__ mu2, const float* __restrict__ va2,
    float* __restrict__ h2)
{
    __shared__ float s1[CIN], t1[CIN];
    __shared__ float s2c[MID], t2c[MID];
    __shared__ float xs[64][68];
    __shared__ float ws[64][64];

    const int tid = threadIdx.x;
    {
        float s = g1[tid] * rsqrtf(va1[tid] + EPS);
        s1[tid] = s;
        t1[tid] = be1[tid] - mu1[tid] * s;
    }
    if (tid < MID) {
        float s = g2[tid] * rsqrtf(va2[tid] + EPS);
        s2c[tid] = s;
        t2c[tid] = be2[tid] - mu2[tid] * s + b1[tid] * s;   // fold conv bias into BN shift
    }
    __syncthreads();

    const int n0 = blockIdx.x * 64;
    const int ty = tid >> 4, tx = tid & 15;
    float acc[4][4] = {};

    for (int kc = 0; kc < 4; ++kc) {
#pragma unroll
        for (int i = 0; i < 4; ++i) {
            int q = tid + i * 256;
            int r = q >> 4, c4 = (q & 15) * 4;
            int c = kc * 64 + c4;
            float4 v = *reinterpret_cast<const float4*>(&x[(size_t)(n0 + r) * CIN + c]);
            float4 o;
            o.x = fmaxf(v.x * s1[c + 0] + t1[c + 0], 0.f);
            o.y = fmaxf(v.y * s1[c + 1] + t1[c + 1], 0.f);
            o.z = fmaxf(v.z * s1[c + 2] + t1[c + 2], 0.f);
            o.w = fmaxf(v.w * s1[c + 3] + t1[c + 3], 0.f);
            *reinterpret_cast<float4*>(&xs[r][c4]) = o;
        }
#pragma unroll
        for (int i = 0; i < 4; ++i) {
            int q = tid + i * 256;
            *reinterpret_cast<float4*>(&ws[0][0] + q * 4) =
                *reinterpret_cast<const float4*>(&w1[(size_t)kc * 64 * MID + q * 4]);
        }
        __syncthreads();
        micro_gemm(xs, ws, ty, tx, acc);
        __syncthreads();
    }

#pragma unroll
    for (int i = 0; i < 4; ++i) {
        int r = n0 + ty * 4 + i;
        int c = tx * 4;
        float4 o;
        o.x = fmaxf(acc[i][0] * s2c[c + 0] + t2c[c + 0], 0.f);
        o.y = fmaxf(acc[i][1] * s2c[c + 1] + t2c[c + 1], 0.f);
        o.z = fmaxf(acc[i][2] * s2c[c + 2] + t2c[c + 2], 0.f);
        o.w = fmaxf(acc[i][3] * s2c[c + 3] + t2c[c + 3], 0.f);
        *reinterpret_cast<float4*>(&h2[(size_t)r * MID + c]) = o;
    }
}

// ---------------------------------------------------------------------------
// K2: h4 = relu(BN3( einsum(gather(h2) * mask, w2) + b2 ))   [N,64] -> [N,64]
// ---------------------------------------------------------------------------
__global__ __launch_bounds__(256) void k2_gather_gemm(
    const float* __restrict__ h2,
    const int* __restrict__ nbr_idx,
    const void* __restrict__ nbr_mask,
    const int* __restrict__ mask_mode,
    const float* __restrict__ w2, const float* __restrict__ b2,
    const float* __restrict__ g3, const float* __restrict__ be3,
    const float* __restrict__ mu3, const float* __restrict__ va3,
    float* __restrict__ h4)
{
    __shared__ float s3c[MID], t3c[MID];
    __shared__ float gs[64][68];
    __shared__ float ws[64][64];
    __shared__ int   idxs[64 * KOFF];
    __shared__ float ms[64 * KOFF];

    const int tid = threadIdx.x;
    const int n0 = blockIdx.x * 64;
    if (tid < MID) {
        float s = g3[tid] * rsqrtf(va3[tid] + EPS);
        s3c[tid] = s;
        t3c[tid] = be3[tid] - mu3[tid] * s + b2[tid] * s;
    }
    const int mode = *mask_mode;   // uniform scalar branch selector
    for (int q = tid; q < 64 * KOFF; q += 256) {
        size_t o = (size_t)n0 * KOFF + q;
        idxs[q] = nbr_idx[o];
        float mv;
        if (mode == 0)
            mv = (((const int*)nbr_mask)[o] != 0) ? 1.f : 0.f;
        else if (mode == 1)
            mv = (((const unsigned char*)nbr_mask)[o] != 0) ? 1.f : 0.f;
        else
            mv = (((const float*)nbr_mask)[o] != 0.f) ? 1.f : 0.f;
        ms[q] = mv;
    }
    __syncthreads();

    const int ty = tid >> 4, tx = tid & 15;
    float acc[4][4] = {};

    for (int k = 0; k < KOFF; ++k) {
#pragma unroll
        for (int i = 0; i < 4; ++i) {
            int q = tid + i * 256;
            *reinterpret_cast<float4*>(&ws[0][0] + q * 4) =
                *reinterpret_cast<const float4*>(&w2[(size_t)k * MID * MID + q * 4]);
        }
        {
            const int c4 = (tid & 15) * 4;
            const int rr = tid >> 4;
#pragma unroll
            for (int it = 0; it < 4; ++it) {
                int r = rr + it * 16;
                int idx = idxs[r * KOFF + k];
                float m = ms[r * KOFF + k];
                float4 v = *reinterpret_cast<const float4*>(&h2[(size_t)idx * MID + c4]);
                v.x *= m; v.y *= m; v.z *= m; v.w *= m;
                *reinterpret_cast<float4*>(&gs[r][c4]) = v;
            }
        }
        __syncthreads();
        micro_gemm(gs, ws, ty, tx, acc);
        __syncthreads();
    }

#pragma unroll
    for (int i = 0; i < 4; ++i) {
        int r = n0 + ty * 4 + i;
        int c = tx * 4;
        float4 o;
        o.x = fmaxf(acc[i][0] * s3c[c + 0] + t3c[c + 0], 0.f);
        o.y = fmaxf(acc[i][1] * s3c[c + 1] + t3c[c + 1], 0.f);
        o.z = fmaxf(acc[i][2] * s3c[c + 2] + t3c[c + 2], 0.f);
        o.w = fmaxf(acc[i][3] * s3c[c + 3] + t3c[c + 3], 0.f);
        *reinterpret_cast<float4*>(&h4[(size_t)r * MID + c]) = o;
    }
}

// ---------------------------------------------------------------------------
// K3: out = h4 @ w3 + b3 + relu(BN1(x))                 [N,64] -> [N,256]
// ---------------------------------------------------------------------------
__global__ __launch_bounds__(256) void k3_gemm_add(
    const float* __restrict__ h4,
    const float* __restrict__ w3, const float* __restrict__ b3,
    const float* __restrict__ x,
    const float* __restrict__ g1, const float* __restrict__ be1,
    const float* __restrict__ mu1, const float* __restrict__ va1,
    float* __restrict__ out)
{
    __shared__ float s1[CIN], t1[CIN], b3s[CIN];
    __shared__ float hs[64][68];
    __shared__ float ws[64][64];

    const int tid = threadIdx.x;
    const int n0 = blockIdx.x * 64;
    {
        float s = g1[tid] * rsqrtf(va1[tid] + EPS);
        s1[tid] = s;
        t1[tid] = be1[tid] - mu1[tid] * s;
        b3s[tid] = b3[tid];
    }
#pragma unroll
    for (int i = 0; i < 4; ++i) {
        int q = tid + i * 256;
        int r = q >> 4, c4 = (q & 15) * 4;
        *reinterpret_cast<float4*>(&hs[r][c4]) =
            *reinterpret_cast<const float4*>(&h4[(size_t)(n0 + r) * MID + c4]);
    }
    __syncthreads();

    const int ty = tid >> 4, tx = tid & 15;
    for (int cc = 0; cc < 4; ++cc) {
#pragma unroll
        for (int i = 0; i < 4; ++i) {
            int q = tid + i * 256;
            int r = q >> 4, c4 = (q & 15) * 4;
            *reinterpret_cast<float4*>(&ws[r][c4]) =
                *reinterpret_cast<const float4*>(&w3[(size_t)r * CIN + cc * 64 + c4]);
        }
        __syncthreads();
        float acc[4][4] = {};
        micro_gemm(hs, ws, ty, tx, acc);
#pragma unroll
        for (int i = 0; i < 4; ++i) {
            int r = n0 + ty * 4 + i;
            int c = cc * 64 + tx * 4;
            float4 xv = *reinterpret_cast<const float4*>(&x[(size_t)r * CIN + c]);
            float4 o;
            o.x = acc[i][0] + b3s[c + 0] + fmaxf(xv.x * s1[c + 0] + t1[c + 0], 0.f);
            o.y = acc[i][1] + b3s[c + 1] + fmaxf(xv.y * s1[c + 1] + t1[c + 1], 0.f);
            o.z = acc[i][2] + b3s[c + 2] + fmaxf(xv.z * s1[c + 2] + t1[c + 2], 0.f);
            o.w = acc[i][3] + b3s[c + 3] + fmaxf(xv.w * s1[c + 3] + t1[c + 3], 0.f);
            *reinterpret_cast<float4*>(&out[(size_t)r * CIN + c]) = o;
        }
        __syncthreads();
    }
}

// ---------------------------------------------------------------------------
extern "C" void kernel_launch(void* const* d_in, const int* in_sizes, int n_in,
                              void* d_out, int out_size, void* d_ws, size_t ws_size,
                              hipStream_t stream)
{
    const float* x    = (const float*)d_in[0];
    const float* g1   = (const float*)d_in[1];
    const float* be1  = (const float*)d_in[2];
    const float* mu1  = (const float*)d_in[3];
    const float* va1  = (const float*)d_in[4];
    const float* w1   = (const float*)d_in[5];
    const float* b1   = (const float*)d_in[6];
    const float* g2   = (const float*)d_in[7];
    const float* be2  = (const float*)d_in[8];
    const float* mu2  = (const float*)d_in[9];
    const float* va2  = (const float*)d_in[10];
    const float* w2   = (const float*)d_in[11];
    const float* b2   = (const float*)d_in[12];
    const float* g3   = (const float*)d_in[13];
    const float* be3  = (const float*)d_in[14];
    const float* mu3  = (const float*)d_in[15];
    const float* va3  = (const float*)d_in[16];
    const float* w3   = (const float*)d_in[17];
    const float* b3   = (const float*)d_in[18];
    const int*   nidx = (const int*)d_in[19];
    const void*  nmask = (const void*)d_in[20];

    float* out  = (float*)d_out;
    int*   flag = (int*)d_ws;                                            // mask mode
    float* h2   = (float*)((char*)d_ws + 256);                           // [N, 64]
    float* h4   = (float*)((char*)d_ws + 256 + (size_t)NTOT * MID * 4);  // [N, 64]

    dim3 grid(NTOT / 64), block(256);
    detect_mask<<<1, 256, 0, stream>>>((const unsigned int*)nmask, flag);
    k1_bn_gemm_bn<<<grid, block, 0, stream>>>(x, g1, be1, mu1, va1, w1, b1,
                                              g2, be2, mu2, va2, h2);
    k2_gather_gemm<<<grid, block, 0, stream>>>(h2, nidx, nmask, flag, w2, b2,
                                               g3, be3, mu3, va3, h4);
    k3_gemm_add<<<grid, block, 0, stream>>>(h4, w3, b3, x, g1, be1, mu1, va1, out);
}